// Round 3
// baseline (1461.655 us; speedup 1.0000x reference)
//
#include <hip/hip_runtime.h>
#include <cstdint>
#include <cstddef>

#define T_ 65536

// ---------------- threefry2x32 (bit-exact vs JAX) ----------------
__device__ __forceinline__ void tf2x32(uint32_t k0, uint32_t k1,
                                       uint32_t& x0, uint32_t& x1) {
  const uint32_t ks[3] = {k0, k1, k0 ^ k1 ^ 0x1BD11BDAu};
  const int R[8] = {13, 15, 26, 6, 17, 29, 16, 24};
  x0 += ks[0]; x1 += ks[1];
#pragma unroll
  for (int i = 0; i < 5; ++i) {
#pragma unroll
    for (int j = 0; j < 4; ++j) {
      const int r = R[(i & 1) * 4 + j];
      x0 += x1;
      x1 = (x1 << r) | (x1 >> (32 - r));
      x1 ^= x0;
    }
    x0 += ks[(i + 1) % 3];
    x1 += ks[(i + 2) % 3] + (uint32_t)(i + 1);
  }
}

__device__ __forceinline__ float gumbel_from_bits(uint32_t b) {
  float u = __uint_as_float((b >> 9) | 0x3f800000u) - 1.0f;
  u = fmaxf(u, 1.17549435e-38f);
  return -logf(-logf(u));
}

// ---------------- coefficient setup (1 block) ----------------
// JAX threefry_partitionable path (default since 0.4.36):
//   split(key,3): key_i = threefry(key, (0,i)) both out words
//   random_bits:  bits_i = o0 ^ o1 of threefry(key, (0,i))
// ws coefs per resonator r: [D1, D2, c1, c2]
__global__ __launch_bounds__(128) void coef_kernel(
    const float* __restrict__ da, const float* __restrict__ fa, const float* __restrict__ ra,
    const float* __restrict__ db, const float* __restrict__ fb, const float* __restrict__ rb,
    const float* __restrict__ dc, const float* __restrict__ fc, const float* __restrict__ rc,
    float* __restrict__ cws) {
  __shared__ float z[128];
  uint32_t keys[3][2];
#pragma unroll
  for (int q = 0; q < 3; ++q) {
    uint32_t x0 = 0u, x1 = (uint32_t)q;
    tf2x32(0u, 42u, x0, x1);
    keys[q][0] = x0; keys[q][1] = x1;
  }
  const float* dl[3] = {da, db, dc};
  const float* fg[3] = {fa, fb, fc};
  const float* rf[3] = {ra, rb, rc};
  const int Ls[3] = {85, 85, 8};
  const int md[3] = {40, 40, 32};
  const int i = threadIdx.x;
  for (int r = 0; r < 3; ++r) {
    const int L = Ls[r];
    z[i] = -3.4e38f;
    __syncthreads();
    if (i < L) {
      uint32_t x0 = 0u, x1 = (uint32_t)i;
      tf2x32(keys[r][0], keys[r][1], x0, x1);
      z[i] = dl[r][i] + gumbel_from_bits(x0 ^ x1);
    }
    __syncthreads();
    if (i == 0) {
      int p = 0; float best = z[0];
      for (int j = 1; j < L; ++j) { float v = z[j]; if (v > best) { best = v; p = j; } }
      const bool lowpass = (r == 2);
      float r0 = rf[r][0], r1 = rf[r][1];
      if (lowpass) { r0 = 1.f / (1.f + expf(-r0)); r1 = 1.f / (1.f + expf(-r1)); }
      else         { r0 = tanhf(r0);               r1 = tanhf(r1); }
      const float k1 = tanhf(r0), k2 = tanhf(r1);
      float a1 = k1 * (1.f - k2);
      const float a2 = fminf(fmaxf(k2, -0.999f), 0.999f);
      const float bnd = 0.999f - fabsf(a2);
      a1 = fminf(fmaxf(a1, -bnd), bnd);
      const float g = powf(1.f / (1.f + expf(-fg[r][0])), 0.45f);
      cws[r * 4 + 0] = (float)(md[r] + p + 1);
      cws[r * 4 + 1] = (float)(md[r] + ((p + 1) % L) + 1);
      cws[r * 4 + 2] = a1 * g;
      cws[r * 4 + 3] = a2 * g;
    }
    __syncthreads();
  }
}

// ---------------- power-cycle-phase prefix sum (fp64 block scan) ----------------
__global__ __launch_bounds__(1024) void pcp_kernel(const float* __restrict__ f0,
                                                   float* __restrict__ pcp) {
  __shared__ double sm[1024];
  const int b = blockIdx.x;
  const int tid = threadIdx.x;
  const float* src = f0 + (size_t)b * T_;
  const int base = tid * 64;
  double loc = 0.0;
  for (int k = 0; k < 64; ++k) {
    loc += 6.283185307179586 * (double)src[base + k] / 48000.0;
  }
  sm[tid] = loc;
  __syncthreads();
  for (int off = 1; off < 1024; off <<= 1) {
    double v = (tid >= off) ? sm[tid - off] : 0.0;
    __syncthreads();
    sm[tid] += v;
    __syncthreads();
  }
  double run = (tid > 0) ? sm[tid - 1] : 0.0;
  float* dst = pcp + (size_t)b * T_;
  for (int k = 0; k < 64; ++k) {
    run += 6.283185307179586 * (double)src[base + k] / 48000.0;
    dst[base + k] = (float)(run * 0.5);
  }
}

// ---------------- harmonic synth + banks (memory-bound) ----------------
__global__ __launch_bounds__(256) void synth_kernel(
    const float* __restrict__ amps,   // (B,512,T)
    const float* __restrict__ fmg,    // (B,1,T)
    const float* __restrict__ cps,    // (B,16,T)
    const float* __restrict__ nba,    // (B,32,T)
    const float* __restrict__ nps,    // (B,2,T)
    const float* __restrict__ npg,    // (B,1,T)
    const float* __restrict__ fng,    // (B,1,T)
    const float* __restrict__ bands,  // (32,T)
    const float* __restrict__ pcp,    // (B,T) ws
    float* __restrict__ bank_a, float* __restrict__ bank_b) {
  const float TPF = 6.283185307179586f;
  const int gid = blockIdx.x * 256 + threadIdx.x;
  const int b = gid >> 15;
  const int t = (gid & 32767) * 2;
  const size_t bt = (size_t)b * T_ + t;
  const float p0 = pcp[bt], p1 = pcp[bt + 1];
  const float fm0 = fmg[bt], fm1 = fmg[bt + 1];

  float nse0 = 0.f, nse1 = 0.f;
  for (int n = 0; n < 32; ++n) {
    const float2 a = *(const float2*)(nba + ((size_t)b * 32 + n) * T_ + t);
    const float2 w = *(const float2*)(bands + (size_t)n * T_ + t);
    nse0 += a.x * w.x; nse1 += a.y * w.y;
  }

  const int order[8] = {0, 4, 3, 7, 5, 2, 6, 1};
  float ha0 = 0, ha1 = 0, hb0 = 0, hb1 = 0;
#pragma unroll
  for (int c = 0; c < 8; ++c) {
    const float ang = ((float)order[c] / 8.0f) * TPF;
    float s0 = p0 + ang; if (s0 >= TPF) s0 -= TPF;
    float s1 = p1 + ang; if (s1 >= TPF) s1 -= TPF;
    const float th0 = TPF * powf(s0 / TPF, fm0);
    const float th1 = TPF * powf(s1 / TPF, fm1);
    float sn0, cs0, sn1, cs1;
    sincosf(th0, &sn0, &cs0);
    sincosf(th1, &sn1, &cs1);
    float sp0 = 0.f, sc0 = sn0, sp1 = 0.f, sc1 = sn1;
    const float tc0 = 2.f * cs0, tc1 = 2.f * cs1;
    float acc0 = 0.f, acc1 = 0.f;
    const float* ap = amps + ((size_t)b * 512 + (size_t)c * 64) * T_ + t;
#pragma unroll 4
    for (int h = 0; h < 64; ++h) {
      const float2 a = *(const float2*)(ap + (size_t)h * T_);
      acc0 += a.x * sc0; acc1 += a.y * sc1;
      const float nx0 = tc0 * sc0 - sp0; sp0 = sc0; sc0 = nx0;
      const float nx1 = tc1 * sc1 - sp1; sp1 = sc1; sc1 = nx1;
    }
    const float2 al = *(const float2*)(cps + ((size_t)b * 16 + c) * T_ + t);
    const float2 be = *(const float2*)(cps + ((size_t)b * 16 + 8 + c) * T_ + t);
    const float env0 = (1.f - expf(-al.x * s0)) * expf(-be.x * s0);
    const float env1 = (1.f - expf(-al.y * s1)) * expf(-be.y * s1);
    const float hh0 = -acc0 * env0 * 10.f;
    const float hh1 = -acc1 * env1 * 10.f;
    if (c < 4) { ha0 += hh0; ha1 += hh1; } else { hb0 += hh0; hb1 += hh1; }
  }

  const float g0 = npg[bt], g1 = npg[bt + 1];
  const float fl0 = fng[bt], fl1 = fng[bt + 1];
  const float na0 = nps[(size_t)b * 2 * T_ + t],     na1 = nps[(size_t)b * 2 * T_ + t + 1];
  const float nb0 = nps[((size_t)b * 2 + 1) * T_ + t], nb1 = nps[((size_t)b * 2 + 1) * T_ + t + 1];
  float q0 = p0; if (q0 >= TPF) q0 -= TPF;
  float q1 = p1; if (q1 >= TPF) q1 -= TPF;
  const float ne0 = (1.f - expf(-na0 * q0)) * expf(-nb0 * q0);
  const float ne1 = (1.f - expf(-na1 * q1)) * expf(-nb1 * q1);
  const float com0 = nse0 * (ne0 * g0 + fl0 * 0.3f);
  const float com1 = nse1 * (ne1 * g1 + fl1 * 0.3f);
  const float K0 = nse0 * (g0 + fl0) * 0.7f;
  const float K1 = nse1 * (g1 + fl1) * 0.7f;
  *(float2*)(bank_a + bt) = make_float2(ha0 * (1.f + K0) + 4.f * com0,
                                        ha1 * (1.f + K1) + 4.f * com1);
  *(float2*)(bank_b + bt) = make_float2(hb0 * (1.f + K0) + 4.f * com0,
                                        hb1 * (1.f + K1) + 4.f * com1);
}

// ---------------- 2-tap comb resonator: wave-synchronous shuffle scan --------
// One wave (64 lanes) per filter instance. Chunk C = min(D1,D2,64) >= 33.
// History of last 4 chunks lives in registers h1..h4 (h_k[lane] = y[(s-k)*C+lane]).
// Tap t-Dj maps to history chunk k = ceil((Dj-o)/C) (loop-invariant per lane)
// at lane o-Dj+k*C. All shuffles issued unconditionally (full-wave lockstep),
// selection via cndmask — no runtime-indexed register arrays (scratch trap).
template <bool TWO_IN>
__device__ __forceinline__ void shuffle_scan(const float* __restrict__ x1,
                                             const float* __restrict__ x2,
                                             float* __restrict__ yo,
                                             const float* __restrict__ cf) {
  const int D1 = (int)cf[0];
  const int D2 = (int)cf[1];
  const float c1 = cf[2], c2 = cf[3];
  const int W = (D1 < D2) ? D1 : D2;      // >= 33
  const int C = (W < 64) ? W : 64;        // chunk size, 33..64
  const int o = threadIdx.x & 63;
  // loop-invariant tap descriptors (garbage for lanes o >= C, never consumed)
  const int k1 = (D1 - o + C - 1) / C;    // 1..4 for lanes < C
  const int s1 = o - D1 + k1 * C;         // 0..C-1 for lanes < C
  const int k2 = (D2 - o + C - 1) / C;
  const int s2 = o - D2 + k2 * C;
  const int S = (T_ + C - 1) / C;
  const bool act = (o < C);
  float h1 = 0.f, h2 = 0.f, h3 = 0.f, h4 = 0.f;
  float xv = 0.f;
  if (act) { xv = x1[o]; if (TWO_IN) xv += x2[o]; }
  for (int s = 0; s < S; ++s) {
    const int t = s * C + o;
    const int tn = t + C;
    float xn = 0.f;
    if (act && tn < T_) { xn = x1[tn]; if (TWO_IN) xn += x2[tn]; }  // prefetch
    // tap 1
    const float a1v = __shfl(h1, s1, 64);
    const float a2v = __shfl(h2, s1, 64);
    const float a3v = __shfl(h3, s1, 64);
    const float a4v = __shfl(h4, s1, 64);
    const float v1 = (k1 == 1) ? a1v : (k1 == 2) ? a2v : (k1 == 3) ? a3v : a4v;
    // tap 2
    const float b1v = __shfl(h1, s2, 64);
    const float b2v = __shfl(h2, s2, 64);
    const float b3v = __shfl(h3, s2, 64);
    const float b4v = __shfl(h4, s2, 64);
    const float v2 = (k2 == 1) ? b1v : (k2 == 2) ? b2v : (k2 == 3) ? b3v : b4v;
    const float y = xv - (c1 * v1 + c2 * v2);
    if (act && t < T_) yo[t] = y;
    h4 = h3; h3 = h2; h2 = h1; h1 = y;
    xv = xn;
  }
}

__global__ __launch_bounds__(64) void res_ab_kernel(
    const float* __restrict__ BA, const float* __restrict__ BB,
    float* __restrict__ RA, float* __restrict__ RB, const float* __restrict__ CW) {
  const int r = blockIdx.x >> 1;
  const int b = blockIdx.x & 1;
  const float* x = (r == 0 ? BA : BB) + (size_t)b * T_;
  float* y = (r == 0 ? RA : RB) + (size_t)b * T_;
  shuffle_scan<false>(x, nullptr, y, CW + r * 4);
}

__global__ __launch_bounds__(64) void res_c_kernel(
    const float* __restrict__ RA, const float* __restrict__ RB,
    float* __restrict__ out, const float* __restrict__ CW) {
  const int b = blockIdx.x;
  shuffle_scan<true>(RA + (size_t)b * T_, RB + (size_t)b * T_, out + (size_t)b * T_, CW + 8);
}

// ---------------- launch ----------------
extern "C" void kernel_launch(void* const* d_in, const int* in_sizes, int n_in,
                              void* d_out, int out_size, void* d_ws, size_t ws_size,
                              hipStream_t stream) {
  const float* f0    = (const float*)d_in[0];
  const float* amps  = (const float*)d_in[1];
  const float* fmg   = (const float*)d_in[2];
  const float* cps   = (const float*)d_in[4];
  const float* nba   = (const float*)d_in[5];
  const float* nps   = (const float*)d_in[6];
  const float* npg   = (const float*)d_in[7];
  const float* fng   = (const float*)d_in[8];
  const float* bands = (const float*)d_in[9];
  const float* da  = (const float*)d_in[10];
  const float* fga = (const float*)d_in[11];
  const float* ra  = (const float*)d_in[12];
  const float* db  = (const float*)d_in[13];
  const float* fgb = (const float*)d_in[14];
  const float* rb  = (const float*)d_in[15];
  const float* dc  = (const float*)d_in[16];
  const float* fgc = (const float*)d_in[17];
  const float* rc  = (const float*)d_in[18];
  float* out = (float*)d_out;
  float* ws  = (float*)d_ws;

  float* W0 = ws;              // pcp, then reused as res_a
  float* W1 = ws + 131072;     // bank_a
  float* W2 = ws + 262144;     // bank_b
  float* W3 = ws + 393216;     // res_b
  float* CW = ws + 524288;     // coefficients

  pcp_kernel<<<2, 1024, 0, stream>>>(f0, W0);
  coef_kernel<<<1, 128, 0, stream>>>(da, fga, ra, db, fgb, rb, dc, fgc, rc, CW);
  synth_kernel<<<256, 256, 0, stream>>>(amps, fmg, cps, nba, nps, npg, fng, bands,
                                        W0, W1, W2);
  res_ab_kernel<<<4, 64, 0, stream>>>(W1, W2, W0, W3, CW);
  res_c_kernel<<<2, 64, 0, stream>>>(W0, W3, out, CW);
}

// Round 4
// 1446.334 us; speedup vs baseline: 1.0106x; 1.0106x over previous
//
#include <hip/hip_runtime.h>
#include <cstdint>
#include <cstddef>

#define T_ 65536

// ---------------- threefry2x32 (bit-exact vs JAX) ----------------
__device__ __forceinline__ void tf2x32(uint32_t k0, uint32_t k1,
                                       uint32_t& x0, uint32_t& x1) {
  const uint32_t ks[3] = {k0, k1, k0 ^ k1 ^ 0x1BD11BDAu};
  const int R[8] = {13, 15, 26, 6, 17, 29, 16, 24};
  x0 += ks[0]; x1 += ks[1];
#pragma unroll
  for (int i = 0; i < 5; ++i) {
#pragma unroll
    for (int j = 0; j < 4; ++j) {
      const int r = R[(i & 1) * 4 + j];
      x0 += x1;
      x1 = (x1 << r) | (x1 >> (32 - r));
      x1 ^= x0;
    }
    x0 += ks[(i + 1) % 3];
    x1 += ks[(i + 2) % 3] + (uint32_t)(i + 1);
  }
}

__device__ __forceinline__ float gumbel_from_bits(uint32_t b) {
  float u = __uint_as_float((b >> 9) | 0x3f800000u) - 1.0f;
  u = fmaxf(u, 1.17549435e-38f);
  return -logf(-logf(u));
}

// ---------------- coefficient setup (1 block) ----------------
// JAX threefry_partitionable path (default since 0.4.36):
//   split(key,3): key_i = threefry(key, (0,i)) both out words
//   random_bits:  bits_i = o0 ^ o1 of threefry(key, (0,i))
// ws coefs per resonator r: [D1, D2, c1, c2]
__global__ __launch_bounds__(128) void coef_kernel(
    const float* __restrict__ da, const float* __restrict__ fa, const float* __restrict__ ra,
    const float* __restrict__ db, const float* __restrict__ fb, const float* __restrict__ rb,
    const float* __restrict__ dc, const float* __restrict__ fc, const float* __restrict__ rc,
    float* __restrict__ cws) {
  __shared__ float z[128];
  uint32_t keys[3][2];
#pragma unroll
  for (int q = 0; q < 3; ++q) {
    uint32_t x0 = 0u, x1 = (uint32_t)q;
    tf2x32(0u, 42u, x0, x1);
    keys[q][0] = x0; keys[q][1] = x1;
  }
  const float* dl[3] = {da, db, dc};
  const float* fg[3] = {fa, fb, fc};
  const float* rf[3] = {ra, rb, rc};
  const int Ls[3] = {85, 85, 8};
  const int md[3] = {40, 40, 32};
  const int i = threadIdx.x;
  for (int r = 0; r < 3; ++r) {
    const int L = Ls[r];
    z[i] = -3.4e38f;
    __syncthreads();
    if (i < L) {
      uint32_t x0 = 0u, x1 = (uint32_t)i;
      tf2x32(keys[r][0], keys[r][1], x0, x1);
      z[i] = dl[r][i] + gumbel_from_bits(x0 ^ x1);
    }
    __syncthreads();
    if (i == 0) {
      int p = 0; float best = z[0];
      for (int j = 1; j < L; ++j) { float v = z[j]; if (v > best) { best = v; p = j; } }
      const bool lowpass = (r == 2);
      float r0 = rf[r][0], r1 = rf[r][1];
      if (lowpass) { r0 = 1.f / (1.f + expf(-r0)); r1 = 1.f / (1.f + expf(-r1)); }
      else         { r0 = tanhf(r0);               r1 = tanhf(r1); }
      const float k1 = tanhf(r0), k2 = tanhf(r1);
      float a1 = k1 * (1.f - k2);
      const float a2 = fminf(fmaxf(k2, -0.999f), 0.999f);
      const float bnd = 0.999f - fabsf(a2);
      a1 = fminf(fmaxf(a1, -bnd), bnd);
      const float g = powf(1.f / (1.f + expf(-fg[r][0])), 0.45f);
      cws[r * 4 + 0] = (float)(md[r] + p + 1);
      cws[r * 4 + 1] = (float)(md[r] + ((p + 1) % L) + 1);
      cws[r * 4 + 2] = a1 * g;
      cws[r * 4 + 3] = a2 * g;
    }
    __syncthreads();
  }
}

// ---------------- power-cycle-phase prefix sum (fp64 block scan) ----------------
__global__ __launch_bounds__(1024) void pcp_kernel(const float* __restrict__ f0,
                                                   float* __restrict__ pcp) {
  __shared__ double sm[1024];
  const int b = blockIdx.x;
  const int tid = threadIdx.x;
  const float* src = f0 + (size_t)b * T_;
  const int base = tid * 64;
  double loc = 0.0;
  for (int k = 0; k < 64; ++k) {
    loc += 6.283185307179586 * (double)src[base + k] / 48000.0;
  }
  sm[tid] = loc;
  __syncthreads();
  for (int off = 1; off < 1024; off <<= 1) {
    double v = (tid >= off) ? sm[tid - off] : 0.0;
    __syncthreads();
    sm[tid] += v;
    __syncthreads();
  }
  double run = (tid > 0) ? sm[tid - 1] : 0.0;
  float* dst = pcp + (size_t)b * T_;
  for (int k = 0; k < 64; ++k) {
    run += 6.283185307179586 * (double)src[base + k] / 48000.0;
    dst[base + k] = (float)(run * 0.5);
  }
}

// ---------------- harmonic synth + banks (memory-bound) ----------------
__global__ __launch_bounds__(256) void synth_kernel(
    const float* __restrict__ amps,   // (B,512,T)
    const float* __restrict__ fmg,    // (B,1,T)
    const float* __restrict__ cps,    // (B,16,T)
    const float* __restrict__ nba,    // (B,32,T)
    const float* __restrict__ nps,    // (B,2,T)
    const float* __restrict__ npg,    // (B,1,T)
    const float* __restrict__ fng,    // (B,1,T)
    const float* __restrict__ bands,  // (32,T)
    const float* __restrict__ pcp,    // (B,T) ws
    float* __restrict__ bank_a, float* __restrict__ bank_b) {
  const float TPF = 6.283185307179586f;
  const int gid = blockIdx.x * 256 + threadIdx.x;
  const int b = gid >> 15;
  const int t = (gid & 32767) * 2;
  const size_t bt = (size_t)b * T_ + t;
  const float p0 = pcp[bt], p1 = pcp[bt + 1];
  const float fm0 = fmg[bt], fm1 = fmg[bt + 1];

  float nse0 = 0.f, nse1 = 0.f;
  for (int n = 0; n < 32; ++n) {
    const float2 a = *(const float2*)(nba + ((size_t)b * 32 + n) * T_ + t);
    const float2 w = *(const float2*)(bands + (size_t)n * T_ + t);
    nse0 += a.x * w.x; nse1 += a.y * w.y;
  }

  const int order[8] = {0, 4, 3, 7, 5, 2, 6, 1};
  float ha0 = 0, ha1 = 0, hb0 = 0, hb1 = 0;
#pragma unroll
  for (int c = 0; c < 8; ++c) {
    const float ang = ((float)order[c] / 8.0f) * TPF;
    float s0 = p0 + ang; if (s0 >= TPF) s0 -= TPF;
    float s1 = p1 + ang; if (s1 >= TPF) s1 -= TPF;
    const float th0 = TPF * powf(s0 / TPF, fm0);
    const float th1 = TPF * powf(s1 / TPF, fm1);
    float sn0, cs0, sn1, cs1;
    sincosf(th0, &sn0, &cs0);
    sincosf(th1, &sn1, &cs1);
    float sp0 = 0.f, sc0 = sn0, sp1 = 0.f, sc1 = sn1;
    const float tc0 = 2.f * cs0, tc1 = 2.f * cs1;
    float acc0 = 0.f, acc1 = 0.f;
    const float* ap = amps + ((size_t)b * 512 + (size_t)c * 64) * T_ + t;
#pragma unroll 4
    for (int h = 0; h < 64; ++h) {
      const float2 a = *(const float2*)(ap + (size_t)h * T_);
      acc0 += a.x * sc0; acc1 += a.y * sc1;
      const float nx0 = tc0 * sc0 - sp0; sp0 = sc0; sc0 = nx0;
      const float nx1 = tc1 * sc1 - sp1; sp1 = sc1; sc1 = nx1;
    }
    const float2 al = *(const float2*)(cps + ((size_t)b * 16 + c) * T_ + t);
    const float2 be = *(const float2*)(cps + ((size_t)b * 16 + 8 + c) * T_ + t);
    const float env0 = (1.f - expf(-al.x * s0)) * expf(-be.x * s0);
    const float env1 = (1.f - expf(-al.y * s1)) * expf(-be.y * s1);
    const float hh0 = -acc0 * env0 * 10.f;
    const float hh1 = -acc1 * env1 * 10.f;
    if (c < 4) { ha0 += hh0; ha1 += hh1; } else { hb0 += hh0; hb1 += hh1; }
  }

  const float g0 = npg[bt], g1 = npg[bt + 1];
  const float fl0 = fng[bt], fl1 = fng[bt + 1];
  const float na0 = nps[(size_t)b * 2 * T_ + t],     na1 = nps[(size_t)b * 2 * T_ + t + 1];
  const float nb0 = nps[((size_t)b * 2 + 1) * T_ + t], nb1 = nps[((size_t)b * 2 + 1) * T_ + t + 1];
  float q0 = p0; if (q0 >= TPF) q0 -= TPF;
  float q1 = p1; if (q1 >= TPF) q1 -= TPF;
  const float ne0 = (1.f - expf(-na0 * q0)) * expf(-nb0 * q0);
  const float ne1 = (1.f - expf(-na1 * q1)) * expf(-nb1 * q1);
  const float com0 = nse0 * (ne0 * g0 + fl0 * 0.3f);
  const float com1 = nse1 * (ne1 * g1 + fl1 * 0.3f);
  const float K0 = nse0 * (g0 + fl0) * 0.7f;
  const float K1 = nse1 * (g1 + fl1) * 0.7f;
  *(float2*)(bank_a + bt) = make_float2(ha0 * (1.f + K0) + 4.f * com0,
                                        ha1 * (1.f + K1) + 4.f * com1);
  *(float2*)(bank_b + bt) = make_float2(hb0 * (1.f + K0) + 4.f * com0,
                                        hb1 * (1.f + K1) + 4.f * com1);
}

// ---------------- 2-tap comb resonator: wave-sync shuffle scan, deep prefetch ----
// One wave per filter. Chunk C = min(D1,D2,64) >= 33. Last 4 chunks of y live in
// registers h1..h4; taps fetched by __shfl. Input prefetched P=16 chunks ahead
// through a fully-unrolled rotating register buffer (static indices only), so
// the ~1000-cycle post-flush HBM latency amortizes to ~60 cy/step.
template <bool TWO_IN>
__device__ __forceinline__ void shuffle_scan(const float* __restrict__ x1,
                                             const float* __restrict__ x2,
                                             float* __restrict__ yo,
                                             const float* __restrict__ cf) {
  const int D1 = (int)cf[0];
  const int D2 = (int)cf[1];
  const float c1 = cf[2], c2 = cf[3];
  const int W = (D1 < D2) ? D1 : D2;      // >= 33
  const int C = (W < 64) ? W : 64;        // chunk size, 33..64
  const int o = threadIdx.x & 63;
  const int k1 = (D1 - o + C - 1) / C;    // history chunk index, 1..4 (lanes < C)
  const int s1 = o - D1 + k1 * C;         // source lane, 0..C-1 (lanes < C)
  const int k2 = (D2 - o + C - 1) / C;
  const int s2 = o - D2 + k2 * C;
  const int S = (T_ + C - 1) / C;
  const bool act = (o < C);
  constexpr int P = 16;

  float xb[P];
#pragma unroll
  for (int p = 0; p < P; ++p) {
    const int t = p * C + o;
    float v = 0.f;
    if (act && t < T_) { v = x1[t]; if (TWO_IN) v += x2[t]; }
    xb[p] = v;
  }

  float h1 = 0.f, h2 = 0.f, h3 = 0.f, h4 = 0.f;
  for (int sb = 0; sb < S; sb += P) {
#pragma unroll
    for (int p = 0; p < P; ++p) {
      const int s = sb + p;
      const float xv = xb[p];
      // re-issue this slot's load P chunks ahead (stays in flight ~P iterations)
      const int tf = (s + P) * C + o;
      float v = 0.f;
      if (act && tf < T_) { v = x1[tf]; if (TWO_IN) v += x2[tf]; }
      xb[p] = v;
      // taps from register history via cross-lane shuffle
      const float a1v = __shfl(h1, s1, 64);
      const float a2v = __shfl(h2, s1, 64);
      const float a3v = __shfl(h3, s1, 64);
      const float a4v = __shfl(h4, s1, 64);
      const float v1 = (k1 == 1) ? a1v : (k1 == 2) ? a2v : (k1 == 3) ? a3v : a4v;
      const float b1v = __shfl(h1, s2, 64);
      const float b2v = __shfl(h2, s2, 64);
      const float b3v = __shfl(h3, s2, 64);
      const float b4v = __shfl(h4, s2, 64);
      const float v2 = (k2 == 1) ? b1v : (k2 == 2) ? b2v : (k2 == 3) ? b3v : b4v;
      const float y = xv - (c1 * v1 + c2 * v2);
      const int t = s * C + o;
      if (act && t < T_) yo[t] = y;
      h4 = h3; h3 = h2; h2 = h1; h1 = y;
    }
  }
}

__global__ __launch_bounds__(64) void res_ab_kernel(
    const float* __restrict__ BA, const float* __restrict__ BB,
    float* __restrict__ RA, float* __restrict__ RB, const float* __restrict__ CW) {
  const int r = blockIdx.x >> 1;
  const int b = blockIdx.x & 1;
  const float* x = (r == 0 ? BA : BB) + (size_t)b * T_;
  float* y = (r == 0 ? RA : RB) + (size_t)b * T_;
  shuffle_scan<false>(x, nullptr, y, CW + r * 4);
}

__global__ __launch_bounds__(64) void res_c_kernel(
    const float* __restrict__ RA, const float* __restrict__ RB,
    float* __restrict__ out, const float* __restrict__ CW) {
  const int b = blockIdx.x;
  shuffle_scan<true>(RA + (size_t)b * T_, RB + (size_t)b * T_, out + (size_t)b * T_, CW + 8);
}

// ---------------- launch ----------------
extern "C" void kernel_launch(void* const* d_in, const int* in_sizes, int n_in,
                              void* d_out, int out_size, void* d_ws, size_t ws_size,
                              hipStream_t stream) {
  const float* f0    = (const float*)d_in[0];
  const float* amps  = (const float*)d_in[1];
  const float* fmg   = (const float*)d_in[2];
  const float* cps   = (const float*)d_in[4];
  const float* nba   = (const float*)d_in[5];
  const float* nps   = (const float*)d_in[6];
  const float* npg   = (const float*)d_in[7];
  const float* fng   = (const float*)d_in[8];
  const float* bands = (const float*)d_in[9];
  const float* da  = (const float*)d_in[10];
  const float* fga = (const float*)d_in[11];
  const float* ra  = (const float*)d_in[12];
  const float* db  = (const float*)d_in[13];
  const float* fgb = (const float*)d_in[14];
  const float* rb  = (const float*)d_in[15];
  const float* dc  = (const float*)d_in[16];
  const float* fgc = (const float*)d_in[17];
  const float* rc  = (const float*)d_in[18];
  float* out = (float*)d_out;
  float* ws  = (float*)d_ws;

  float* W0 = ws;              // pcp, then reused as res_a
  float* W1 = ws + 131072;     // bank_a
  float* W2 = ws + 262144;     // bank_b
  float* W3 = ws + 393216;     // res_b
  float* CW = ws + 524288;     // coefficients

  pcp_kernel<<<2, 1024, 0, stream>>>(f0, W0);
  coef_kernel<<<1, 128, 0, stream>>>(da, fga, ra, db, fgb, rb, dc, fgc, rc, CW);
  synth_kernel<<<256, 256, 0, stream>>>(amps, fmg, cps, nba, nps, npg, fng, bands,
                                        W0, W1, W2);
  res_ab_kernel<<<4, 64, 0, stream>>>(W1, W2, W0, W3, CW);
  res_c_kernel<<<2, 64, 0, stream>>>(W0, W3, out, CW);
}

// Round 5
// 870.123 us; speedup vs baseline: 1.6798x; 1.6622x over previous
//
#include <hip/hip_runtime.h>
#include <cstdint>
#include <cstddef>

#define T_ 65536

// ---------------- threefry2x32 (bit-exact vs JAX) ----------------
__device__ __forceinline__ void tf2x32(uint32_t k0, uint32_t k1,
                                       uint32_t& x0, uint32_t& x1) {
  const uint32_t ks[3] = {k0, k1, k0 ^ k1 ^ 0x1BD11BDAu};
  const int R[8] = {13, 15, 26, 6, 17, 29, 16, 24};
  x0 += ks[0]; x1 += ks[1];
#pragma unroll
  for (int i = 0; i < 5; ++i) {
#pragma unroll
    for (int j = 0; j < 4; ++j) {
      const int r = R[(i & 1) * 4 + j];
      x0 += x1;
      x1 = (x1 << r) | (x1 >> (32 - r));
      x1 ^= x0;
    }
    x0 += ks[(i + 1) % 3];
    x1 += ks[(i + 2) % 3] + (uint32_t)(i + 1);
  }
}

__device__ __forceinline__ float gumbel_from_bits(uint32_t b) {
  float u = __uint_as_float((b >> 9) | 0x3f800000u) - 1.0f;
  u = fmaxf(u, 1.17549435e-38f);
  return -logf(-logf(u));
}

// ---------------- coefficient setup (1 block) ----------------
// JAX threefry_partitionable path (default since 0.4.36):
//   split(key,3): key_i = threefry(key, (0,i)) both out words
//   random_bits:  bits_i = o0 ^ o1 of threefry(key, (0,i))
// ws coefs per resonator r: [D1, D2, c1, c2]
__global__ __launch_bounds__(128) void coef_kernel(
    const float* __restrict__ da, const float* __restrict__ fa, const float* __restrict__ ra,
    const float* __restrict__ db, const float* __restrict__ fb, const float* __restrict__ rb,
    const float* __restrict__ dc, const float* __restrict__ fc, const float* __restrict__ rc,
    float* __restrict__ cws) {
  __shared__ float z[128];
  uint32_t keys[3][2];
#pragma unroll
  for (int q = 0; q < 3; ++q) {
    uint32_t x0 = 0u, x1 = (uint32_t)q;
    tf2x32(0u, 42u, x0, x1);
    keys[q][0] = x0; keys[q][1] = x1;
  }
  const float* dl[3] = {da, db, dc};
  const float* fg[3] = {fa, fb, fc};
  const float* rf[3] = {ra, rb, rc};
  const int Ls[3] = {85, 85, 8};
  const int md[3] = {40, 40, 32};
  const int i = threadIdx.x;
  for (int r = 0; r < 3; ++r) {
    const int L = Ls[r];
    z[i] = -3.4e38f;
    __syncthreads();
    if (i < L) {
      uint32_t x0 = 0u, x1 = (uint32_t)i;
      tf2x32(keys[r][0], keys[r][1], x0, x1);
      z[i] = dl[r][i] + gumbel_from_bits(x0 ^ x1);
    }
    __syncthreads();
    if (i == 0) {
      int p = 0; float best = z[0];
      for (int j = 1; j < L; ++j) { float v = z[j]; if (v > best) { best = v; p = j; } }
      const bool lowpass = (r == 2);
      float r0 = rf[r][0], r1 = rf[r][1];
      if (lowpass) { r0 = 1.f / (1.f + expf(-r0)); r1 = 1.f / (1.f + expf(-r1)); }
      else         { r0 = tanhf(r0);               r1 = tanhf(r1); }
      const float k1 = tanhf(r0), k2 = tanhf(r1);
      float a1 = k1 * (1.f - k2);
      const float a2 = fminf(fmaxf(k2, -0.999f), 0.999f);
      const float bnd = 0.999f - fabsf(a2);
      a1 = fminf(fmaxf(a1, -bnd), bnd);
      const float g = powf(1.f / (1.f + expf(-fg[r][0])), 0.45f);
      cws[r * 4 + 0] = (float)(md[r] + p + 1);
      cws[r * 4 + 1] = (float)(md[r] + ((p + 1) % L) + 1);
      cws[r * 4 + 2] = a1 * g;
      cws[r * 4 + 3] = a2 * g;
    }
    __syncthreads();
  }
}

// ---------------- power-cycle-phase prefix sum (fp64 block scan) ----------------
__global__ __launch_bounds__(1024) void pcp_kernel(const float* __restrict__ f0,
                                                   float* __restrict__ pcp) {
  __shared__ double sm[1024];
  const int b = blockIdx.x;
  const int tid = threadIdx.x;
  const float* src = f0 + (size_t)b * T_;
  const int base = tid * 64;
  double loc = 0.0;
  for (int k = 0; k < 64; ++k) {
    loc += 6.283185307179586 * (double)src[base + k] / 48000.0;
  }
  sm[tid] = loc;
  __syncthreads();
  for (int off = 1; off < 1024; off <<= 1) {
    double v = (tid >= off) ? sm[tid - off] : 0.0;
    __syncthreads();
    sm[tid] += v;
    __syncthreads();
  }
  double run = (tid > 0) ? sm[tid - 1] : 0.0;
  float* dst = pcp + (size_t)b * T_;
  for (int k = 0; k < 64; ++k) {
    run += 6.283185307179586 * (double)src[base + k] / 48000.0;
    dst[base + k] = (float)(run * 0.5);
  }
}

// ---------------- harmonic synth + banks (memory-bound) ----------------
__global__ __launch_bounds__(256) void synth_kernel(
    const float* __restrict__ amps,   // (B,512,T)
    const float* __restrict__ fmg,    // (B,1,T)
    const float* __restrict__ cps,    // (B,16,T)
    const float* __restrict__ nba,    // (B,32,T)
    const float* __restrict__ nps,    // (B,2,T)
    const float* __restrict__ npg,    // (B,1,T)
    const float* __restrict__ fng,    // (B,1,T)
    const float* __restrict__ bands,  // (32,T)
    const float* __restrict__ pcp,    // (B,T) ws
    float* __restrict__ bank_a, float* __restrict__ bank_b) {
  const float TPF = 6.283185307179586f;
  const int gid = blockIdx.x * 256 + threadIdx.x;
  const int b = gid >> 15;
  const int t = (gid & 32767) * 2;
  const size_t bt = (size_t)b * T_ + t;
  const float p0 = pcp[bt], p1 = pcp[bt + 1];
  const float fm0 = fmg[bt], fm1 = fmg[bt + 1];

  float nse0 = 0.f, nse1 = 0.f;
  for (int n = 0; n < 32; ++n) {
    const float2 a = *(const float2*)(nba + ((size_t)b * 32 + n) * T_ + t);
    const float2 w = *(const float2*)(bands + (size_t)n * T_ + t);
    nse0 += a.x * w.x; nse1 += a.y * w.y;
  }

  const int order[8] = {0, 4, 3, 7, 5, 2, 6, 1};
  float ha0 = 0, ha1 = 0, hb0 = 0, hb1 = 0;
#pragma unroll
  for (int c = 0; c < 8; ++c) {
    const float ang = ((float)order[c] / 8.0f) * TPF;
    float s0 = p0 + ang; if (s0 >= TPF) s0 -= TPF;
    float s1 = p1 + ang; if (s1 >= TPF) s1 -= TPF;
    const float th0 = TPF * powf(s0 / TPF, fm0);
    const float th1 = TPF * powf(s1 / TPF, fm1);
    float sn0, cs0, sn1, cs1;
    sincosf(th0, &sn0, &cs0);
    sincosf(th1, &sn1, &cs1);
    float sp0 = 0.f, sc0 = sn0, sp1 = 0.f, sc1 = sn1;
    const float tc0 = 2.f * cs0, tc1 = 2.f * cs1;
    float acc0 = 0.f, acc1 = 0.f;
    const float* ap = amps + ((size_t)b * 512 + (size_t)c * 64) * T_ + t;
#pragma unroll 4
    for (int h = 0; h < 64; ++h) {
      const float2 a = *(const float2*)(ap + (size_t)h * T_);
      acc0 += a.x * sc0; acc1 += a.y * sc1;
      const float nx0 = tc0 * sc0 - sp0; sp0 = sc0; sc0 = nx0;
      const float nx1 = tc1 * sc1 - sp1; sp1 = sc1; sc1 = nx1;
    }
    const float2 al = *(const float2*)(cps + ((size_t)b * 16 + c) * T_ + t);
    const float2 be = *(const float2*)(cps + ((size_t)b * 16 + 8 + c) * T_ + t);
    const float env0 = (1.f - expf(-al.x * s0)) * expf(-be.x * s0);
    const float env1 = (1.f - expf(-al.y * s1)) * expf(-be.y * s1);
    const float hh0 = -acc0 * env0 * 10.f;
    const float hh1 = -acc1 * env1 * 10.f;
    if (c < 4) { ha0 += hh0; ha1 += hh1; } else { hb0 += hh0; hb1 += hh1; }
  }

  const float g0 = npg[bt], g1 = npg[bt + 1];
  const float fl0 = fng[bt], fl1 = fng[bt + 1];
  const float na0 = nps[(size_t)b * 2 * T_ + t],     na1 = nps[(size_t)b * 2 * T_ + t + 1];
  const float nb0 = nps[((size_t)b * 2 + 1) * T_ + t], nb1 = nps[((size_t)b * 2 + 1) * T_ + t + 1];
  float q0 = p0; if (q0 >= TPF) q0 -= TPF;
  float q1 = p1; if (q1 >= TPF) q1 -= TPF;
  const float ne0 = (1.f - expf(-na0 * q0)) * expf(-nb0 * q0);
  const float ne1 = (1.f - expf(-na1 * q1)) * expf(-nb1 * q1);
  const float com0 = nse0 * (ne0 * g0 + fl0 * 0.3f);
  const float com1 = nse1 * (ne1 * g1 + fl1 * 0.3f);
  const float K0 = nse0 * (g0 + fl0) * 0.7f;
  const float K1 = nse1 * (g1 + fl1) * 0.7f;
  *(float2*)(bank_a + bt) = make_float2(ha0 * (1.f + K0) + 4.f * com0,
                                        ha1 * (1.f + K1) + 4.f * com1);
  *(float2*)(bank_b + bt) = make_float2(hb0 * (1.f + K0) + 4.f * com0,
                                        hb1 * (1.f + K1) + 4.f * com1);
}

// ---------------- 2-tap comb resonator: wave-sync shuffle scan ----------------
// One wave per filter. Chunk C = min(D1,D2,64) >= 33. Last 4 chunks of y live
// in registers h1..h4; taps via __shfl. Input is double-buffered in blocks of
// P=16 chunks: all loads are UNCONDITIONAL with clamped addresses (branch-free)
// so SIInsertWaitcnts can emit counted s_waitcnt vmcnt(N) instead of the
// per-step vmcnt(0) drain that conditional (exec-branchy) loads force — that
// drain was the entire 1012 us cost of rounds 2-4. Garbage lanes/steps are
// never consumed: stores stay predicated, taps only read lanes < C.
template <bool TWO_IN>
__device__ __forceinline__ float ld_clamped(const float* __restrict__ x1,
                                            const float* __restrict__ x2, int t) {
  const int tc = (t < T_) ? t : (T_ - 1);   // branch-free VALU select
  float v = x1[tc];
  if (TWO_IN) v += x2[tc];
  return v;
}

template <bool TWO_IN>
__device__ __forceinline__ void shuffle_scan(const float* __restrict__ x1,
                                             const float* __restrict__ x2,
                                             float* __restrict__ yo,
                                             const float* __restrict__ cf) {
  const int D1 = (int)cf[0];
  const int D2 = (int)cf[1];
  const float c1 = cf[2], c2 = cf[3];
  const int W = (D1 < D2) ? D1 : D2;      // >= 33
  const int C = (W < 64) ? W : 64;        // chunk size, 33..64
  const int o = threadIdx.x & 63;
  const int k1 = (D1 - o + C - 1) / C;    // history chunk index, 1..4 (lanes < C)
  const int s1 = o - D1 + k1 * C;         // source lane, 0..C-1 (lanes < C)
  const int k2 = (D2 - o + C - 1) / C;
  const int s2 = o - D2 + k2 * C;
  const int S = (T_ + C - 1) / C;         // chunks of real work
  const bool act = (o < C);
  constexpr int P = 16;

  float h1 = 0.f, h2 = 0.f, h3 = 0.f, h4 = 0.f;

#define STEP_BODY(XV, SIDX)                                                  \
  {                                                                          \
    const float a1v = __shfl(h1, s1, 64);                                    \
    const float a2v = __shfl(h2, s1, 64);                                    \
    const float a3v = __shfl(h3, s1, 64);                                    \
    const float a4v = __shfl(h4, s1, 64);                                    \
    const float v1 = (k1 == 1) ? a1v : (k1 == 2) ? a2v : (k1 == 3) ? a3v : a4v; \
    const float b1v = __shfl(h1, s2, 64);                                    \
    const float b2v = __shfl(h2, s2, 64);                                    \
    const float b3v = __shfl(h3, s2, 64);                                    \
    const float b4v = __shfl(h4, s2, 64);                                    \
    const float v2 = (k2 == 1) ? b1v : (k2 == 2) ? b2v : (k2 == 3) ? b3v : b4v; \
    const float y = (XV) - (c1 * v1 + c2 * v2);                              \
    const int tt = (SIDX) * C + o;                                           \
    if (act && tt < T_) yo[tt] = y;                                          \
    h4 = h3; h3 = h2; h2 = h1; h1 = y;                                       \
  }

  float A[P], Bf[P];
#pragma unroll
  for (int p = 0; p < P; ++p) A[p] = ld_clamped<TWO_IN>(x1, x2, p * C + o);

  const int nblk = (S + P - 1) / P;       // number of P-chunk blocks (round up)
  for (int blk = 0; blk < nblk; blk += 2) {
    // group-issue next block's loads (unconditional, clamped)
#pragma unroll
    for (int p = 0; p < P; ++p)
      Bf[p] = ld_clamped<TWO_IN>(x1, x2, ((blk + 1) * P + p) * C + o);
    // 16 scan steps from A (waits are counted: >=16 guaranteed newer loads)
#pragma unroll
    for (int p = 0; p < P; ++p) STEP_BODY(A[p], blk * P + p);
#pragma unroll
    for (int p = 0; p < P; ++p)
      A[p] = ld_clamped<TWO_IN>(x1, x2, ((blk + 2) * P + p) * C + o);
#pragma unroll
    for (int p = 0; p < P; ++p) STEP_BODY(Bf[p], (blk + 1) * P + p);
  }
#undef STEP_BODY
}

__global__ __launch_bounds__(64) void res_ab_kernel(
    const float* __restrict__ BA, const float* __restrict__ BB,
    float* __restrict__ RA, float* __restrict__ RB, const float* __restrict__ CW) {
  const int r = blockIdx.x >> 1;
  const int b = blockIdx.x & 1;
  const float* x = (r == 0 ? BA : BB) + (size_t)b * T_;
  float* y = (r == 0 ? RA : RB) + (size_t)b * T_;
  shuffle_scan<false>(x, nullptr, y, CW + r * 4);
}

__global__ __launch_bounds__(64) void res_c_kernel(
    const float* __restrict__ RA, const float* __restrict__ RB,
    float* __restrict__ out, const float* __restrict__ CW) {
  const int b = blockIdx.x;
  shuffle_scan<true>(RA + (size_t)b * T_, RB + (size_t)b * T_, out + (size_t)b * T_, CW + 8);
}

// ---------------- launch ----------------
extern "C" void kernel_launch(void* const* d_in, const int* in_sizes, int n_in,
                              void* d_out, int out_size, void* d_ws, size_t ws_size,
                              hipStream_t stream) {
  const float* f0    = (const float*)d_in[0];
  const float* amps  = (const float*)d_in[1];
  const float* fmg   = (const float*)d_in[2];
  const float* cps   = (const float*)d_in[4];
  const float* nba   = (const float*)d_in[5];
  const float* nps   = (const float*)d_in[6];
  const float* npg   = (const float*)d_in[7];
  const float* fng   = (const float*)d_in[8];
  const float* bands = (const float*)d_in[9];
  const float* da  = (const float*)d_in[10];
  const float* fga = (const float*)d_in[11];
  const float* ra  = (const float*)d_in[12];
  const float* db  = (const float*)d_in[13];
  const float* fgb = (const float*)d_in[14];
  const float* rb  = (const float*)d_in[15];
  const float* dc  = (const float*)d_in[16];
  const float* fgc = (const float*)d_in[17];
  const float* rc  = (const float*)d_in[18];
  float* out = (float*)d_out;
  float* ws  = (float*)d_ws;

  float* W0 = ws;              // pcp, then reused as res_a
  float* W1 = ws + 131072;     // bank_a
  float* W2 = ws + 262144;     // bank_b
  float* W3 = ws + 393216;     // res_b
  float* CW = ws + 524288;     // coefficients

  pcp_kernel<<<2, 1024, 0, stream>>>(f0, W0);
  coef_kernel<<<1, 128, 0, stream>>>(da, fga, ra, db, fgb, rb, dc, fgc, rc, CW);
  synth_kernel<<<256, 256, 0, stream>>>(amps, fmg, cps, nba, nps, npg, fng, bands,
                                        W0, W1, W2);
  res_ab_kernel<<<4, 64, 0, stream>>>(W1, W2, W0, W3, CW);
  res_c_kernel<<<2, 64, 0, stream>>>(W0, W3, out, CW);
}

// Round 6
// 850.495 us; speedup vs baseline: 1.7186x; 1.0231x over previous
//
#include <hip/hip_runtime.h>
#include <cstdint>
#include <cstddef>

#define T_ 65536

// ---------------- threefry2x32 (bit-exact vs JAX) ----------------
__device__ __forceinline__ void tf2x32(uint32_t k0, uint32_t k1,
                                       uint32_t& x0, uint32_t& x1) {
  const uint32_t ks[3] = {k0, k1, k0 ^ k1 ^ 0x1BD11BDAu};
  const int R[8] = {13, 15, 26, 6, 17, 29, 16, 24};
  x0 += ks[0]; x1 += ks[1];
#pragma unroll
  for (int i = 0; i < 5; ++i) {
#pragma unroll
    for (int j = 0; j < 4; ++j) {
      const int r = R[(i & 1) * 4 + j];
      x0 += x1;
      x1 = (x1 << r) | (x1 >> (32 - r));
      x1 ^= x0;
    }
    x0 += ks[(i + 1) % 3];
    x1 += ks[(i + 2) % 3] + (uint32_t)(i + 1);
  }
}

__device__ __forceinline__ float gumbel_from_bits(uint32_t b) {
  float u = __uint_as_float((b >> 9) | 0x3f800000u) - 1.0f;
  u = fmaxf(u, 1.17549435e-38f);
  return -logf(-logf(u));
}

// ---------------- coefficient setup (1 block) ----------------
// JAX threefry_partitionable path (default since 0.4.36).
// ws coefs per resonator r: [D1, D2, c1, c2]
__global__ __launch_bounds__(128) void coef_kernel(
    const float* __restrict__ da, const float* __restrict__ fa, const float* __restrict__ ra,
    const float* __restrict__ db, const float* __restrict__ fb, const float* __restrict__ rb,
    const float* __restrict__ dc, const float* __restrict__ fc, const float* __restrict__ rc,
    float* __restrict__ cws) {
  __shared__ float z[128];
  uint32_t keys[3][2];
#pragma unroll
  for (int q = 0; q < 3; ++q) {
    uint32_t x0 = 0u, x1 = (uint32_t)q;
    tf2x32(0u, 42u, x0, x1);
    keys[q][0] = x0; keys[q][1] = x1;
  }
  const float* dl[3] = {da, db, dc};
  const float* fg[3] = {fa, fb, fc};
  const float* rf[3] = {ra, rb, rc};
  const int Ls[3] = {85, 85, 8};
  const int md[3] = {40, 40, 32};
  const int i = threadIdx.x;
  for (int r = 0; r < 3; ++r) {
    const int L = Ls[r];
    z[i] = -3.4e38f;
    __syncthreads();
    if (i < L) {
      uint32_t x0 = 0u, x1 = (uint32_t)i;
      tf2x32(keys[r][0], keys[r][1], x0, x1);
      z[i] = dl[r][i] + gumbel_from_bits(x0 ^ x1);
    }
    __syncthreads();
    if (i == 0) {
      int p = 0; float best = z[0];
      for (int j = 1; j < L; ++j) { float v = z[j]; if (v > best) { best = v; p = j; } }
      const bool lowpass = (r == 2);
      float r0 = rf[r][0], r1 = rf[r][1];
      if (lowpass) { r0 = 1.f / (1.f + expf(-r0)); r1 = 1.f / (1.f + expf(-r1)); }
      else         { r0 = tanhf(r0);               r1 = tanhf(r1); }
      const float k1 = tanhf(r0), k2 = tanhf(r1);
      float a1 = k1 * (1.f - k2);
      const float a2 = fminf(fmaxf(k2, -0.999f), 0.999f);
      const float bnd = 0.999f - fabsf(a2);
      a1 = fminf(fmaxf(a1, -bnd), bnd);
      const float g = powf(1.f / (1.f + expf(-fg[r][0])), 0.45f);
      cws[r * 4 + 0] = (float)(md[r] + p + 1);
      cws[r * 4 + 1] = (float)(md[r] + ((p + 1) % L) + 1);
      cws[r * 4 + 2] = a1 * g;
      cws[r * 4 + 3] = a2 * g;
    }
    __syncthreads();
  }
}

// ---------------- power-cycle-phase prefix sum (fp64 block scan) ----------------
__global__ __launch_bounds__(1024) void pcp_kernel(const float* __restrict__ f0,
                                                   float* __restrict__ pcp) {
  __shared__ double sm[1024];
  const int b = blockIdx.x;
  const int tid = threadIdx.x;
  const float* src = f0 + (size_t)b * T_;
  const int base = tid * 64;
  double loc = 0.0;
  for (int k = 0; k < 64; ++k) {
    loc += 6.283185307179586 * (double)src[base + k] / 48000.0;
  }
  sm[tid] = loc;
  __syncthreads();
  for (int off = 1; off < 1024; off <<= 1) {
    double v = (tid >= off) ? sm[tid - off] : 0.0;
    __syncthreads();
    sm[tid] += v;
    __syncthreads();
  }
  double run = (tid > 0) ? sm[tid - 1] : 0.0;
  float* dst = pcp + (size_t)b * T_;
  for (int k = 0; k < 64; ++k) {
    run += 6.283185307179586 * (double)src[base + k] / 48000.0;
    dst[base + k] = (float)(run * 0.5);
  }
}

// ---------------- harmonic synth + banks (memory-bound) ----------------
__global__ __launch_bounds__(256) void synth_kernel(
    const float* __restrict__ amps,   // (B,512,T)
    const float* __restrict__ fmg,    // (B,1,T)
    const float* __restrict__ cps,    // (B,16,T)
    const float* __restrict__ nba,    // (B,32,T)
    const float* __restrict__ nps,    // (B,2,T)
    const float* __restrict__ npg,    // (B,1,T)
    const float* __restrict__ fng,    // (B,1,T)
    const float* __restrict__ bands,  // (32,T)
    const float* __restrict__ pcp,    // (B,T) ws
    float* __restrict__ bank_a, float* __restrict__ bank_b) {
  const float TPF = 6.283185307179586f;
  const int gid = blockIdx.x * 256 + threadIdx.x;
  const int b = gid >> 15;
  const int t = (gid & 32767) * 2;
  const size_t bt = (size_t)b * T_ + t;
  const float p0 = pcp[bt], p1 = pcp[bt + 1];
  const float fm0 = fmg[bt], fm1 = fmg[bt + 1];

  float nse0 = 0.f, nse1 = 0.f;
  for (int n = 0; n < 32; ++n) {
    const float2 a = *(const float2*)(nba + ((size_t)b * 32 + n) * T_ + t);
    const float2 w = *(const float2*)(bands + (size_t)n * T_ + t);
    nse0 += a.x * w.x; nse1 += a.y * w.y;
  }

  const int order[8] = {0, 4, 3, 7, 5, 2, 6, 1};
  float ha0 = 0, ha1 = 0, hb0 = 0, hb1 = 0;
#pragma unroll
  for (int c = 0; c < 8; ++c) {
    const float ang = ((float)order[c] / 8.0f) * TPF;
    float s0 = p0 + ang; if (s0 >= TPF) s0 -= TPF;
    float s1 = p1 + ang; if (s1 >= TPF) s1 -= TPF;
    const float th0 = TPF * powf(s0 / TPF, fm0);
    const float th1 = TPF * powf(s1 / TPF, fm1);
    float sn0, cs0, sn1, cs1;
    sincosf(th0, &sn0, &cs0);
    sincosf(th1, &sn1, &cs1);
    float sp0 = 0.f, sc0 = sn0, sp1 = 0.f, sc1 = sn1;
    const float tc0 = 2.f * cs0, tc1 = 2.f * cs1;
    float acc0 = 0.f, acc1 = 0.f;
    const float* ap = amps + ((size_t)b * 512 + (size_t)c * 64) * T_ + t;
#pragma unroll 4
    for (int h = 0; h < 64; ++h) {
      const float2 a = *(const float2*)(ap + (size_t)h * T_);
      acc0 += a.x * sc0; acc1 += a.y * sc1;
      const float nx0 = tc0 * sc0 - sp0; sp0 = sc0; sc0 = nx0;
      const float nx1 = tc1 * sc1 - sp1; sp1 = sc1; sc1 = nx1;
    }
    const float2 al = *(const float2*)(cps + ((size_t)b * 16 + c) * T_ + t);
    const float2 be = *(const float2*)(cps + ((size_t)b * 16 + 8 + c) * T_ + t);
    const float env0 = (1.f - expf(-al.x * s0)) * expf(-be.x * s0);
    const float env1 = (1.f - expf(-al.y * s1)) * expf(-be.y * s1);
    const float hh0 = -acc0 * env0 * 10.f;
    const float hh1 = -acc1 * env1 * 10.f;
    if (c < 4) { ha0 += hh0; ha1 += hh1; } else { hb0 += hh0; hb1 += hh1; }
  }

  const float g0 = npg[bt], g1 = npg[bt + 1];
  const float fl0 = fng[bt], fl1 = fng[bt + 1];
  const float na0 = nps[(size_t)b * 2 * T_ + t],     na1 = nps[(size_t)b * 2 * T_ + t + 1];
  const float nb0 = nps[((size_t)b * 2 + 1) * T_ + t], nb1 = nps[((size_t)b * 2 + 1) * T_ + t + 1];
  float q0 = p0; if (q0 >= TPF) q0 -= TPF;
  float q1 = p1; if (q1 >= TPF) q1 -= TPF;
  const float ne0 = (1.f - expf(-na0 * q0)) * expf(-nb0 * q0);
  const float ne1 = (1.f - expf(-na1 * q1)) * expf(-nb1 * q1);
  const float com0 = nse0 * (ne0 * g0 + fl0 * 0.3f);
  const float com1 = nse1 * (ne1 * g1 + fl1 * 0.3f);
  const float K0 = nse0 * (g0 + fl0) * 0.7f;
  const float K1 = nse1 * (g1 + fl1) * 0.7f;
  *(float2*)(bank_a + bt) = make_float2(ha0 * (1.f + K0) + 4.f * com0,
                                        ha1 * (1.f + K1) + 4.f * com1);
  *(float2*)(bank_b + bt) = make_float2(hb0 * (1.f + K0) + 4.f * com0,
                                        hb1 * (1.f + K1) + 4.f * com1);
}

// ---------------- 2-tap comb resonator: wave-sync shuffle scan ----------------
// One wave per filter. Chunk C = min(D1,D2,64) >= 33. Last 4 chunks of y in
// registers h1..h4; taps via __shfl. Input double-buffered in blocks of P=16
// chunks. CRITICAL (round-5 post-mortem): issue loops contain ONLY raw loads
// into separate register arrays — the x1+x2 combine and any predication are
// deferred to the consumption step, so the issue loop has no load consumer and
// the compiler emits counted s_waitcnt vmcnt(N) instead of per-load drains.
// Stores are branch-free: inactive/tail lanes store to a per-block dump.
template <bool TWO_IN>
__device__ __forceinline__ void shuffle_scan(const float* __restrict__ x1,
                                             const float* __restrict__ x2,
                                             float* __restrict__ yo,
                                             const float* __restrict__ cf,
                                             float* __restrict__ dump) {
  const int D1 = (int)cf[0];
  const int D2 = (int)cf[1];
  const float c1 = cf[2], c2 = cf[3];
  const int W = (D1 < D2) ? D1 : D2;      // >= 33
  const int C = (W < 64) ? W : 64;        // chunk size, 33..64
  const int o = threadIdx.x & 63;
  const int k1 = (D1 - o + C - 1) / C;    // history chunk index, 1..4 (lanes < C)
  const int s1 = o - D1 + k1 * C;         // source lane, 0..C-1 (lanes < C)
  const int k2 = (D2 - o + C - 1) / C;
  const int s2 = o - D2 + k2 * C;
  const int S = (T_ + C - 1) / C;         // chunks of real work
  const bool act = (o < C);
  constexpr int P = 16;

  float h1 = 0.f, h2 = 0.f, h3 = 0.f, h4 = 0.f;

  // raw load (no combine, no predication — clamped address only)
#define LD1(dst, t)  { const int tc_ = ((t) < T_) ? (t) : (T_ - 1); dst = x1[tc_]; }
#define LD2(dst, t)  { const int tc_ = ((t) < T_) ? (t) : (T_ - 1); dst = x2[tc_]; }

#define STEP_BODY(X1V, X2V, SIDX)                                            \
  {                                                                          \
    const float xv = TWO_IN ? ((X1V) + (X2V)) : (X1V);                       \
    const float a1v = __shfl(h1, s1, 64);                                    \
    const float a2v = __shfl(h2, s1, 64);                                    \
    const float a3v = __shfl(h3, s1, 64);                                    \
    const float a4v = __shfl(h4, s1, 64);                                    \
    const float v1 = (k1 == 1) ? a1v : (k1 == 2) ? a2v : (k1 == 3) ? a3v : a4v; \
    const float b1v = __shfl(h1, s2, 64);                                    \
    const float b2v = __shfl(h2, s2, 64);                                    \
    const float b3v = __shfl(h3, s2, 64);                                    \
    const float b4v = __shfl(h4, s2, 64);                                    \
    const float v2 = (k2 == 1) ? b1v : (k2 == 2) ? b2v : (k2 == 3) ? b3v : b4v; \
    const float y = xv - (c1 * v1 + c2 * v2);                                \
    const int tt = (SIDX) * C + o;                                           \
    float* sp = (act && tt < T_) ? (yo + tt) : (dump + o);  /* branch-free */\
    *sp = y;                                                                 \
    h4 = h3; h3 = h2; h2 = h1; h1 = y;                                       \
  }

  float A1[P], A2[P], B1[P], B2[P];
#pragma unroll
  for (int p = 0; p < P; ++p) LD1(A1[p], p * C + o);
  if (TWO_IN) {
#pragma unroll
    for (int p = 0; p < P; ++p) LD2(A2[p], p * C + o);
  }

  const int nblk = (S + P - 1) / P;
  for (int blk = 0; blk < nblk; blk += 2) {
    // group-issue next block's raw loads
#pragma unroll
    for (int p = 0; p < P; ++p) LD1(B1[p], ((blk + 1) * P + p) * C + o);
    if (TWO_IN) {
#pragma unroll
      for (int p = 0; p < P; ++p) LD2(B2[p], ((blk + 1) * P + p) * C + o);
    }
    // 16 scan steps from A
#pragma unroll
    for (int p = 0; p < P; ++p) STEP_BODY(A1[p], A2[p], blk * P + p);
    // re-issue A for blk+2
#pragma unroll
    for (int p = 0; p < P; ++p) LD1(A1[p], ((blk + 2) * P + p) * C + o);
    if (TWO_IN) {
#pragma unroll
      for (int p = 0; p < P; ++p) LD2(A2[p], ((blk + 2) * P + p) * C + o);
    }
    // 16 scan steps from B
#pragma unroll
    for (int p = 0; p < P; ++p) STEP_BODY(B1[p], B2[p], (blk + 1) * P + p);
  }
#undef STEP_BODY
#undef LD1
#undef LD2
}

__global__ __launch_bounds__(64) void res_ab_kernel(
    const float* __restrict__ BA, const float* __restrict__ BB,
    float* __restrict__ RA, float* __restrict__ RB, const float* __restrict__ CW,
    float* __restrict__ dump) {
  const int r = blockIdx.x >> 1;
  const int b = blockIdx.x & 1;
  const float* x = (r == 0 ? BA : BB) + (size_t)b * T_;
  float* y = (r == 0 ? RA : RB) + (size_t)b * T_;
  shuffle_scan<false>(x, nullptr, y, CW + r * 4, dump + blockIdx.x * 64);
}

__global__ __launch_bounds__(64) void res_c_kernel(
    const float* __restrict__ RA, const float* __restrict__ RB,
    float* __restrict__ out, const float* __restrict__ CW,
    float* __restrict__ dump) {
  const int b = blockIdx.x;
  shuffle_scan<true>(RA + (size_t)b * T_, RB + (size_t)b * T_, out + (size_t)b * T_,
                     CW + 8, dump + blockIdx.x * 64);
}

// ---------------- launch ----------------
extern "C" void kernel_launch(void* const* d_in, const int* in_sizes, int n_in,
                              void* d_out, int out_size, void* d_ws, size_t ws_size,
                              hipStream_t stream) {
  const float* f0    = (const float*)d_in[0];
  const float* amps  = (const float*)d_in[1];
  const float* fmg   = (const float*)d_in[2];
  const float* cps   = (const float*)d_in[4];
  const float* nba   = (const float*)d_in[5];
  const float* nps   = (const float*)d_in[6];
  const float* npg   = (const float*)d_in[7];
  const float* fng   = (const float*)d_in[8];
  const float* bands = (const float*)d_in[9];
  const float* da  = (const float*)d_in[10];
  const float* fga = (const float*)d_in[11];
  const float* ra  = (const float*)d_in[12];
  const float* db  = (const float*)d_in[13];
  const float* fgb = (const float*)d_in[14];
  const float* rb  = (const float*)d_in[15];
  const float* dc  = (const float*)d_in[16];
  const float* fgc = (const float*)d_in[17];
  const float* rc  = (const float*)d_in[18];
  float* out = (float*)d_out;
  float* ws  = (float*)d_ws;

  float* W0 = ws;              // pcp, then reused as res_a
  float* W1 = ws + 131072;     // bank_a
  float* W2 = ws + 262144;     // bank_b
  float* W3 = ws + 393216;     // res_b
  float* CW = ws + 524288;     // coefficients (16 floats)
  float* DP = ws + 524320;     // dump scratch (4 blocks * 64 lanes)

  pcp_kernel<<<2, 1024, 0, stream>>>(f0, W0);
  coef_kernel<<<1, 128, 0, stream>>>(da, fga, ra, db, fgb, rb, dc, fgc, rc, CW);
  synth_kernel<<<256, 256, 0, stream>>>(amps, fmg, cps, nba, nps, npg, fng, bands,
                                        W0, W1, W2);
  res_ab_kernel<<<4, 64, 0, stream>>>(W1, W2, W0, W3, CW, DP);
  res_c_kernel<<<2, 64, 0, stream>>>(W0, W3, out, CW, DP);
}